// Round 2
// baseline (1356.809 us; speedup 1.0000x reference)
//
#include <hip/hip_runtime.h>
#include <hip/hip_bf16.h>
#include <hip/hip_cooperative_groups.h>
#include <math.h>

namespace cg = cooperative_groups;

// Problem constants
#define BATCH   128
#define DMODEL  1024
#define NHEADS  16
#define HEADDIM 64
#define DFF     4096
#define MEMLEN  1024
#define SPLIT   16         // flash-decode m-splits (2048 jobs)
#define CHUNK   (MEMLEN / SPLIT)
#define QSPLIT  8          // split-K for Wq / Wo (kchunk 128, 4 iters)
#define F1SPLIT 4          // split-K for ff1   (kchunk 256, 8 iters)
#define F2SPLIT 16         // split-K for ff2   (kchunk 256, 8 iters)

typedef __attribute__((ext_vector_type(8))) __bf16 bf16x8;
typedef __attribute__((ext_vector_type(4))) __bf16 bf16x4;
typedef __attribute__((ext_vector_type(4))) float  f32x4;

struct Params {
    const float *x, *mk, *mv, *ab;
    const float *Wq, *bq, *Wo, *bo, *W1, *b1, *W2, *b2, *g1, *be1, *g2, *be2;
    float* out;
    float *qpart, *qsum, *tmppart, *hbuf, *ffbpart, *tmp2part, *pacc, *pl;
    __bf16 *attnb, *hbf, *ff1act;
};

// ---------------------------------------------------------------------------
// Split-K GEMM phase as a grid-stride job loop. Job = (n-tile, m-tile, z).
// Tile BM=64, BN=64, BK=32; 256 threads = 4 waves; double-buffered LDS,
// register prefetch, ONE barrier per K-step. ABF16: A is bf16 (load bf16x8
// directly, no cvt); else fp32 (load float4 pair, cvt after MFMA).
// Writes fp32 partials C[z][M][N] (+bias on z==0); consumers sum partials.
// ---------------------------------------------------------------------------
template<int ABF16, int NXLOG2, int KCHUNK>
__device__ __forceinline__ void gemm_phase(
    const float* __restrict__ Af, const __bf16* __restrict__ Ab,
    const float* __restrict__ W, const float* __restrict__ bias,
    float* __restrict__ C, int N, int K, int J, int NB,
    __bf16 (&As)[2][64 * 56], __bf16 (&Bs)[2][64 * 56])
{
    const int t    = threadIdx.x;
    const int lane = t & 63;
    const int w    = t >> 6;
    const int ar = t >> 2, ac = (t & 3) * 8;   // A staging coords
    const int bn = t & 63, bk = w * 8;         // B staging coords
    const int q = lane >> 4, l15 = lane & 15;  // fragment coords
    constexpr int ITERS = KCHUNK / 32;

    for (int job = blockIdx.x; job < J; job += NB) {
        const int nxi  = job & ((1 << NXLOG2) - 1);
        const int rest = job >> NXLOG2;
        const int my   = rest & 1;
        const int z    = rest >> 1;
        const int n0 = nxi * 64, m0 = my * 64, kbeg = z * KCHUNK;

        __syncthreads();   // LDS reuse guard vs previous job

        f32x4 acc[4] = {f32x4{0,0,0,0}, f32x4{0,0,0,0}, f32x4{0,0,0,0}, f32x4{0,0,0,0}};

        const float* wB   = W + (size_t)(kbeg + bk) * N + n0 + bn;
        const size_t aOff = (size_t)(m0 + ar) * K + kbeg + ac;

        // ---- prologue: stage tile 0 into buffer 0
        {
            bf16x8 av;
            if constexpr (ABF16) {
                av = *(const bf16x8*)(Ab + aOff);
            } else {
                const float* ap = Af + aOff;
                float4 a0 = *(const float4*)ap, a1 = *(const float4*)(ap + 4);
                av[0]=(__bf16)a0.x; av[1]=(__bf16)a0.y; av[2]=(__bf16)a0.z; av[3]=(__bf16)a0.w;
                av[4]=(__bf16)a1.x; av[5]=(__bf16)a1.y; av[6]=(__bf16)a1.z; av[7]=(__bf16)a1.w;
            }
            bf16x8 bv;
            #pragma unroll
            for (int j = 0; j < 8; j++) bv[j] = (__bf16)wB[(size_t)j * N];
            *(bf16x8*)&As[0][ar * 56 + ac] = av;
            *(bf16x8*)&Bs[0][bn * 56 + bk] = bv;
        }
        __syncthreads();

        int cur = 0;
        #pragma unroll
        for (int it = 1; it < ITERS; ++it) {
            // ---- prefetch next tile (issue before MFMAs; latency hides)
            bf16x8 avn;
            float ax[8];
            if constexpr (ABF16) {
                avn = *(const bf16x8*)(Ab + aOff + it * 32);
            } else {
                const float* ap = Af + aOff + it * 32;
                float4 a0 = *(const float4*)ap, a1 = *(const float4*)(ap + 4);
                ax[0]=a0.x; ax[1]=a0.y; ax[2]=a0.z; ax[3]=a0.w;
                ax[4]=a1.x; ax[5]=a1.y; ax[6]=a1.z; ax[7]=a1.w;
            }
            float br[8];
            const float* wp = wB + (size_t)(it * 32) * N;
            #pragma unroll
            for (int j = 0; j < 8; j++) br[j] = wp[(size_t)j * N];

            // ---- compute current tile
            bf16x8 af = *(const bf16x8*)&As[cur][(w * 16 + l15) * 56 + q * 8];
            #pragma unroll
            for (int c = 0; c < 4; c++) {
                bf16x8 bfv = *(const bf16x8*)&Bs[cur][(c * 16 + l15) * 56 + q * 8];
                acc[c] = __builtin_amdgcn_mfma_f32_16x16x32_bf16(af, bfv, acc[c], 0, 0, 0);
            }

            // ---- stage next tile
            if constexpr (!ABF16) {
                #pragma unroll
                for (int j = 0; j < 8; j++) avn[j] = (__bf16)ax[j];
            }
            bf16x8 bvn;
            #pragma unroll
            for (int j = 0; j < 8; j++) bvn[j] = (__bf16)br[j];
            *(bf16x8*)&As[cur ^ 1][ar * 56 + ac] = avn;
            *(bf16x8*)&Bs[cur ^ 1][bn * 56 + bk] = bvn;
            __syncthreads();
            cur ^= 1;
        }

        // ---- final tile
        {
            bf16x8 af = *(const bf16x8*)&As[cur][(w * 16 + l15) * 56 + q * 8];
            #pragma unroll
            for (int c = 0; c < 4; c++) {
                bf16x8 bfv = *(const bf16x8*)&Bs[cur][(c * 16 + l15) * 56 + q * 8];
                acc[c] = __builtin_amdgcn_mfma_f32_16x16x32_bf16(af, bfv, acc[c], 0, 0, 0);
            }
        }

        // ---- epilogue: C/D layout col=lane&15, row=(lane>>4)*4+reg [m89]
        float* Cp = C + (size_t)z * ((size_t)BATCH * N);
        #pragma unroll
        for (int c = 0; c < 4; c++) {
            const int col = n0 + c * 16 + l15;
            const float bb = (z == 0) ? bias[col] : 0.0f;
            #pragma unroll
            for (int r = 0; r < 4; r++) {
                const int row = m0 + w * 16 + q * 4 + r;
                Cp[(size_t)row * N + col] = acc[c][r] + bb;
            }
        }
    }
}

// out = LN(x + sum_z parts[z]) * g + be; optional extra bf16 copy of output.
template<int NPARTS, bool WRITE_BF16>
__device__ __forceinline__ void ln_phase(
    const float* __restrict__ xres, const float* __restrict__ parts,
    const float* __restrict__ g, const float* __restrict__ be,
    float* __restrict__ of32, __bf16* __restrict__ obf,
    int NB, float (&red)[8])
{
    const int t = threadIdx.x;
    for (int b = blockIdx.x; b < BATCH; b += NB) {
        float4 sv = *(const float4*)&xres[(size_t)b * DMODEL + 4 * t];
        #pragma unroll
        for (int z = 0; z < NPARTS; z++) {
            const float4 yv = *(const float4*)
                &parts[(size_t)z * (BATCH * DMODEL) + (size_t)b * DMODEL + 4 * t];
            sv.x += yv.x; sv.y += yv.y; sv.z += yv.z; sv.w += yv.w;
        }
        float sum = sv.x + sv.y + sv.z + sv.w;
        float sq  = sv.x * sv.x + sv.y * sv.y + sv.z * sv.z + sv.w * sv.w;
        #pragma unroll
        for (int mask = 1; mask < 64; mask <<= 1) {
            sum += __shfl_xor(sum, mask);
            sq  += __shfl_xor(sq, mask);
        }
        __syncthreads();   // guard red vs any prior use
        if ((t & 63) == 0) { red[(t >> 6) * 2] = sum; red[(t >> 6) * 2 + 1] = sq; }
        __syncthreads();
        sum = red[0] + red[2] + red[4] + red[6];
        sq  = red[1] + red[3] + red[5] + red[7];

        const float mu  = sum * (1.0f / DMODEL);
        const float var = sq * (1.0f / DMODEL) - mu * mu;
        const float rs  = rsqrtf(var + 1e-5f);

        const float4 gv  = *(const float4*)&g[4 * t];
        const float4 bev = *(const float4*)&be[4 * t];
        float4 o;
        o.x = (sv.x - mu) * rs * gv.x + bev.x;
        o.y = (sv.y - mu) * rs * gv.y + bev.y;
        o.z = (sv.z - mu) * rs * gv.z + bev.z;
        o.w = (sv.w - mu) * rs * gv.w + bev.w;
        *(float4*)&of32[(size_t)b * DMODEL + 4 * t] = o;
        if constexpr (WRITE_BF16) {
            bf16x4 ob;
            ob[0] = (__bf16)o.x; ob[1] = (__bf16)o.y;
            ob[2] = (__bf16)o.z; ob[3] = (__bf16)o.w;
            *(bf16x4*)&obf[(size_t)b * DMODEL + 4 * t] = ob;
        }
    }
}

// ---------------------------------------------------------------------------
// One persistent cooperative kernel = the whole transformer block.
// Phases separated by grid.sync(); all phases are grid-stride job loops so
// any co-resident grid size is correct.
// ---------------------------------------------------------------------------
__global__ __launch_bounds__(256) void fused_k(Params p)
{
    __shared__ __bf16 As[2][64 * 56];
    __shared__ __bf16 Bs[2][64 * 56];
    __shared__ float  red[8];

    cg::grid_group grid = cg::this_grid();
    const int NB = gridDim.x;
    const int t  = threadIdx.x;

    // -- 1. q partials = x @ Wq + bq  (fp32 A)
    gemm_phase<0, 4, DMODEL / QSPLIT>(p.x, nullptr, p.Wq, p.bq, p.qpart,
                                      DMODEL, DMODEL, 16 * 2 * QSPLIT, NB, As, Bs);
    grid.sync();

    // -- 1.5 qsum = 0.125 * sum_z qpart[z]  (pre-scaled q)
    for (int b = blockIdx.x; b < BATCH; b += NB) {
        const size_t idx = (size_t)b * DMODEL + 4 * t;
        float4 a = {0.f, 0.f, 0.f, 0.f};
        #pragma unroll
        for (int z = 0; z < QSPLIT; z++) {
            const float4 v = *(const float4*)&p.qpart[(size_t)z * (BATCH * DMODEL) + idx];
            a.x += v.x; a.y += v.y; a.z += v.z; a.w += v.w;
        }
        a.x *= 0.125f; a.y *= 0.125f; a.z *= 0.125f; a.w *= 0.125f;
        *(float4*)&p.qsum[idx] = a;
    }
    grid.sync();

    // -- 2. flash-decode attention partials (the 1 GB K/V stream).
    // Scores bounded (|q.k/8| + |alibi| < ~8) => direct exp, no online max.
    for (int job = blockIdx.x; job < SPLIT * BATCH; job += NB) {
        const int s = job & (SPLIT - 1);
        const int b = job >> 4;
        const int h = t >> 4;

        const float4 qv = *(const float4*)&p.qsum[(size_t)b * DMODEL + 4 * t];
        float  l   = 0.0f;
        f32x4  acc = {0.f, 0.f, 0.f, 0.f};

        const size_t base = (size_t)b * MEMLEN * DMODEL + 4 * t;
        const float* __restrict__ ali = p.ab + (size_t)h * MEMLEN + s * CHUNK;
        const size_t off0 = base + (size_t)(s * CHUNK) * DMODEL;

        #pragma unroll 4
        for (int i = 0; i < CHUNK; i++) {
            const size_t off = off0 + (size_t)i * DMODEL;
            const float4 kv = *(const float4*)&p.mk[off];
            const float4 vv = *(const float4*)&p.mv[off];
            float d = kv.x * qv.x + kv.y * qv.y + kv.z * qv.z + kv.w * qv.w;
            d += __shfl_xor(d, 1);
            d += __shfl_xor(d, 2);
            d += __shfl_xor(d, 4);
            d += __shfl_xor(d, 8);
            const float pw = __expf(d + ali[i]);
            l += pw;
            acc.x += pw * vv.x;
            acc.y += pw * vv.y;
            acc.z += pw * vv.z;
            acc.w += pw * vv.w;
        }
        *(f32x4*)&p.pacc[((size_t)(b * SPLIT + s)) * DMODEL + 4 * t] = acc;
        if ((t & 15) == 0) p.pl[(b * SPLIT + s) * NHEADS + h] = l;
    }
    grid.sync();

    // -- 3. combine partials -> attn (bf16, ready for Wo's A-stage)
    for (int b = blockIdx.x; b < BATCH; b += NB) {
        const int h = t >> 4;
        float  L   = 0.0f;
        float4 acc = {0.f, 0.f, 0.f, 0.f};
        #pragma unroll 4
        for (int s = 0; s < SPLIT; s++) {
            L += p.pl[(b * SPLIT + s) * NHEADS + h];
            const float4 pa = *(const float4*)
                &p.pacc[((size_t)(b * SPLIT + s)) * DMODEL + 4 * t];
            acc.x += pa.x; acc.y += pa.y; acc.z += pa.z; acc.w += pa.w;
        }
        const float inv = 1.0f / L;
        bf16x4 o;
        o[0] = (__bf16)(acc.x * inv); o[1] = (__bf16)(acc.y * inv);
        o[2] = (__bf16)(acc.z * inv); o[3] = (__bf16)(acc.w * inv);
        *(bf16x4*)&p.attnb[(size_t)b * DMODEL + 4 * t] = o;
    }
    grid.sync();

    // -- 4. attn-proj partials = attn @ Wo + bo  (bf16 A)
    gemm_phase<1, 4, DMODEL / QSPLIT>(nullptr, p.attnb, p.Wo, p.bo, p.tmppart,
                                      DMODEL, DMODEL, 16 * 2 * QSPLIT, NB, As, Bs);
    grid.sync();

    // -- 5. h = LN(x + attn_proj); write fp32 (for residual) + bf16 (for ff1)
    ln_phase<QSPLIT, true>(p.x, p.tmppart, p.g1, p.be1, p.hbuf, p.hbf, NB, red);
    grid.sync();

    // -- 6. ff1 partials = h @ W1 + b1  (bf16 A; pre-activation)
    gemm_phase<1, 6, DMODEL / F1SPLIT>(nullptr, p.hbf, p.W1, p.b1, p.ffbpart,
                                       DFF, DMODEL, 64 * 2 * F1SPLIT, NB, As, Bs);
    grid.sync();

    // -- 6.5 ff1act = relu(sum_z ffbpart[z]) as bf16 (ff2's A operand)
    for (int job = blockIdx.x; job < (BATCH * DFF) / 2048; job += NB) {
        const size_t base = (size_t)job * 2048 + t * 8;
        float4 s0 = {0.f, 0.f, 0.f, 0.f}, s1 = {0.f, 0.f, 0.f, 0.f};
        #pragma unroll
        for (int z = 0; z < F1SPLIT; z++) {
            const float* pp = p.ffbpart + (size_t)z * ((size_t)BATCH * DFF) + base;
            const float4 a = *(const float4*)pp;
            const float4 b4 = *(const float4*)(pp + 4);
            s0.x += a.x;  s0.y += a.y;  s0.z += a.z;  s0.w += a.w;
            s1.x += b4.x; s1.y += b4.y; s1.z += b4.z; s1.w += b4.w;
        }
        bf16x8 o;
        o[0] = (__bf16)fmaxf(s0.x, 0.f); o[1] = (__bf16)fmaxf(s0.y, 0.f);
        o[2] = (__bf16)fmaxf(s0.z, 0.f); o[3] = (__bf16)fmaxf(s0.w, 0.f);
        o[4] = (__bf16)fmaxf(s1.x, 0.f); o[5] = (__bf16)fmaxf(s1.y, 0.f);
        o[6] = (__bf16)fmaxf(s1.z, 0.f); o[7] = (__bf16)fmaxf(s1.w, 0.f);
        *(bf16x8*)&p.ff1act[base] = o;
    }
    grid.sync();

    // -- 7. ff2 partials = ff1act @ W2 + b2  (bf16 A)
    gemm_phase<1, 4, DFF / F2SPLIT>(nullptr, p.ff1act, p.W2, p.b2, p.tmp2part,
                                    DMODEL, DFF, 16 * 2 * F2SPLIT, NB, As, Bs);
    grid.sync();

    // -- 8. out = LN(h + ff2)
    ln_phase<F2SPLIT, false>(p.hbuf, p.tmp2part, p.g2, p.be2, p.out, nullptr, NB, red);
}

// ---------------------------------------------------------------------------
extern "C" void kernel_launch(void* const* d_in, const int* in_sizes, int n_in,
                              void* d_out, int out_size, void* d_ws, size_t ws_size,
                              hipStream_t stream)
{
    float* wsf = (float*)d_ws;

    Params P;
    P.x   = (const float*)d_in[0];
    P.mk  = (const float*)d_in[1];
    P.mv  = (const float*)d_in[2];
    P.ab  = (const float*)d_in[3];
    P.Wq  = (const float*)d_in[4];
    P.bq  = (const float*)d_in[5];
    P.Wo  = (const float*)d_in[6];
    P.bo  = (const float*)d_in[7];
    P.W1  = (const float*)d_in[8];
    P.b1  = (const float*)d_in[9];
    P.W2  = (const float*)d_in[10];
    P.b2  = (const float*)d_in[11];
    P.g1  = (const float*)d_in[12];
    P.be1 = (const float*)d_in[13];
    P.g2  = (const float*)d_in[14];
    P.be2 = (const float*)d_in[15];
    P.out = (float*)d_out;

    // Workspace layout (floats); every buffer fully written before read.
    P.qpart    = wsf;                    // 8 x 131072 = 1048576
    P.qsum     = wsf + 1048576;          // 131072
    P.tmppart  = wsf + 1179648;          // 8 x 131072 = 1048576
    P.hbuf     = wsf + 2228224;          // 131072
    P.ffbpart  = wsf + 2359296;          // 4 x 524288 = 2097152
    P.tmp2part = wsf + 4456448;          // 16 x 131072 = 2097152
    P.pacc     = wsf + 6553600;          // 2097152
    P.pl       = wsf + 8650752;          // 32768
    P.attnb    = (__bf16*)(wsf + 8683520);   // 131072 bf16
    P.hbf      = (__bf16*)(wsf + 8749056);   // 131072 bf16
    P.ff1act   = (__bf16*)(wsf + 8814592);   // 524288 bf16

    // Grid = exactly the co-resident capacity (cooperative requirement).
    static int NB = 0;
    if (NB == 0) {
        int per = 0;
        if (hipOccupancyMaxActiveBlocksPerMultiprocessor(
                &per, (const void*)fused_k, 256, 0) != hipSuccess || per < 1)
            per = 2;                      // conservative fallback (LDS 28.7KB -> >=2 fits)
        NB = per * 256;                   // 256 CUs on MI355X
        if (NB > 2048) NB = 2048;
    }

    void* args[] = { (void*)&P };
    hipLaunchCooperativeKernel((const void*)fused_k, dim3(NB), dim3(256),
                               args, 0, stream);
}

// Round 3
// 1054.846 us; speedup vs baseline: 1.2863x; 1.2863x over previous
//
#include <hip/hip_runtime.h>
#include <hip/hip_bf16.h>
#include <math.h>

// Problem constants
#define BATCH   128
#define DMODEL  1024
#define NHEADS  16
#define HEADDIM 64
#define DFF     4096
#define MEMLEN  1024
#define SPLIT   8          // flash-decode m-splits (1024 blocks)
#define CHUNK   (MEMLEN / SPLIT)
#define QSPLIT  8          // split-K for Wq / Wo (kchunk 128, 4 iters, 256 blocks)
#define F1SPLIT 4          // split-K for ff1    (kchunk 256, 8 iters, 512 blocks)
#define F2SPLIT 16         // split-K for ff2    (kchunk 256, 8 iters, 512 blocks)

typedef __attribute__((ext_vector_type(8))) __bf16 bf16x8;
typedef __attribute__((ext_vector_type(4))) __bf16 bf16x4;
typedef __attribute__((ext_vector_type(4))) float  f32x4;

// ---------------------------------------------------------------------------
// Split-K GEMM: Cpart[z][M x N] = A[M x kchunk] @ W + (z==0 ? bias : 0).
// Grid (N/64, M/64, ZSPLIT), 256 threads = 4 waves. Tile BM=64,BN=64,BK=32.
// Double-buffered LDS, register prefetch, ONE barrier per K-step.
// ABF16: A is bf16 (one bf16x8 load, no cvt); else fp32 (float4 pair).
// LDS row stride 56 bf16 (112 B): b128-aligned, 2-way bank alias = free.
// ---------------------------------------------------------------------------
template<int ABF16, int KCHUNK>
__global__ __launch_bounds__(256) void gemm_k(
    const float* __restrict__ Af, const __bf16* __restrict__ Ab,
    const float* __restrict__ W, const float* __restrict__ bias,
    float* __restrict__ C, int N, int K)
{
    const int t    = threadIdx.x;
    const int lane = t & 63;
    const int w    = t >> 6;
    const int n0   = blockIdx.x * 64;
    const int m0   = blockIdx.y * 64;
    const int z    = blockIdx.z;
    const int kbeg = z * KCHUNK;

    __shared__ __bf16 As[2][64 * 56];
    __shared__ __bf16 Bs[2][64 * 56];

    const int ar = t >> 2, ac = (t & 3) * 8;   // A staging coords
    const int bn = t & 63, bk = w * 8;         // B staging coords (transposed)
    const int q = lane >> 4, l15 = lane & 15;  // fragment coords
    constexpr int ITERS = KCHUNK / 32;

    f32x4 acc[4] = {f32x4{0,0,0,0}, f32x4{0,0,0,0}, f32x4{0,0,0,0}, f32x4{0,0,0,0}};

    const float* wB   = W + (size_t)(kbeg + bk) * N + n0 + bn;
    const size_t aOff = (size_t)(m0 + ar) * K + kbeg + ac;

    // ---- prologue: stage tile 0 into buffer 0
    {
        bf16x8 av;
        if constexpr (ABF16) {
            av = *(const bf16x8*)(Ab + aOff);
        } else {
            const float* ap = Af + aOff;
            float4 a0 = *(const float4*)ap, a1 = *(const float4*)(ap + 4);
            av[0]=(__bf16)a0.x; av[1]=(__bf16)a0.y; av[2]=(__bf16)a0.z; av[3]=(__bf16)a0.w;
            av[4]=(__bf16)a1.x; av[5]=(__bf16)a1.y; av[6]=(__bf16)a1.z; av[7]=(__bf16)a1.w;
        }
        bf16x8 bv;
        #pragma unroll
        for (int j = 0; j < 8; j++) bv[j] = (__bf16)wB[(size_t)j * N];
        *(bf16x8*)&As[0][ar * 56 + ac] = av;
        *(bf16x8*)&Bs[0][bn * 56 + bk] = bv;
    }
    __syncthreads();

    int cur = 0;
    #pragma unroll
    for (int it = 1; it < ITERS; ++it) {
        // ---- prefetch next tile (issued before MFMAs; HBM latency hides)
        bf16x8 avn;
        float ax[8];
        if constexpr (ABF16) {
            avn = *(const bf16x8*)(Ab + aOff + it * 32);
        } else {
            const float* ap = Af + aOff + it * 32;
            float4 a0 = *(const float4*)ap, a1 = *(const float4*)(ap + 4);
            ax[0]=a0.x; ax[1]=a0.y; ax[2]=a0.z; ax[3]=a0.w;
            ax[4]=a1.x; ax[5]=a1.y; ax[6]=a1.z; ax[7]=a1.w;
        }
        float br[8];
        const float* wp = wB + (size_t)(it * 32) * N;
        #pragma unroll
        for (int j = 0; j < 8; j++) br[j] = wp[(size_t)j * N];

        // ---- compute current tile
        bf16x8 af = *(const bf16x8*)&As[cur][(w * 16 + l15) * 56 + q * 8];
        #pragma unroll
        for (int c = 0; c < 4; c++) {
            bf16x8 bfv = *(const bf16x8*)&Bs[cur][(c * 16 + l15) * 56 + q * 8];
            acc[c] = __builtin_amdgcn_mfma_f32_16x16x32_bf16(af, bfv, acc[c], 0, 0, 0);
        }

        // ---- stage next tile
        if constexpr (!ABF16) {
            #pragma unroll
            for (int j = 0; j < 8; j++) avn[j] = (__bf16)ax[j];
        }
        bf16x8 bvn;
        #pragma unroll
        for (int j = 0; j < 8; j++) bvn[j] = (__bf16)br[j];
        *(bf16x8*)&As[cur ^ 1][ar * 56 + ac] = avn;
        *(bf16x8*)&Bs[cur ^ 1][bn * 56 + bk] = bvn;
        __syncthreads();
        cur ^= 1;
    }

    // ---- final tile
    {
        bf16x8 af = *(const bf16x8*)&As[cur][(w * 16 + l15) * 56 + q * 8];
        #pragma unroll
        for (int c = 0; c < 4; c++) {
            bf16x8 bfv = *(const bf16x8*)&Bs[cur][(c * 16 + l15) * 56 + q * 8];
            acc[c] = __builtin_amdgcn_mfma_f32_16x16x32_bf16(af, bfv, acc[c], 0, 0, 0);
        }
    }

    // ---- epilogue: C/D layout col=lane&15, row=(lane>>4)*4+reg [m89]
    float* Cp = C + (size_t)z * ((size_t)BATCH * N);
    #pragma unroll
    for (int c = 0; c < 4; c++) {
        const int col = n0 + c * 16 + l15;
        const float bb = (z == 0) ? bias[col] : 0.0f;
        #pragma unroll
        for (int r = 0; r < 4; r++) {
            const int row = m0 + w * 16 + q * 4 + r;
            Cp[(size_t)row * N + col] = acc[c][r] + bb;
        }
    }
}

// qsum = 0.125 * sum_z qpart[z]  (pre-scaled q). Grid 128, 256 threads.
__global__ __launch_bounds__(256) void qsum_k(
    const float* __restrict__ qpart, float* __restrict__ qsum)
{
    const int b = blockIdx.x;
    const int t = threadIdx.x;
    const size_t idx = (size_t)b * DMODEL + 4 * t;
    float4 a = {0.f, 0.f, 0.f, 0.f};
    #pragma unroll
    for (int z = 0; z < QSPLIT; z++) {
        const float4 v = *(const float4*)&qpart[(size_t)z * (BATCH * DMODEL) + idx];
        a.x += v.x; a.y += v.y; a.z += v.z; a.w += v.w;
    }
    a.x *= 0.125f; a.y *= 0.125f; a.z *= 0.125f; a.w *= 0.125f;
    *(float4*)&qsum[idx] = a;
}

// ---------------------------------------------------------------------------
// Flash-decode attention partials. Grid (SPLIT, BATCH), 256 threads.
// Thread t owns dims [4t,4t+4) -> head h = t>>4. Scores bounded
// (|q.k/8| + |alibi| < ~8) => direct exp, no online-max chain.
// ---------------------------------------------------------------------------
__global__ __launch_bounds__(256) void attn_partial_k(
    const float* __restrict__ qsum, const float* __restrict__ Kd,
    const float* __restrict__ Vd, const float* __restrict__ alibi,
    float* __restrict__ pacc, float* __restrict__ pl)
{
    const int s = blockIdx.x;
    const int b = blockIdx.y;
    const int t = threadIdx.x;
    const int h = t >> 4;

    const float4 qv = *(const float4*)&qsum[(size_t)b * DMODEL + 4 * t];
    float  l   = 0.0f;
    f32x4  acc = {0.f, 0.f, 0.f, 0.f};

    const size_t base = (size_t)b * MEMLEN * DMODEL + 4 * t;
    const float* __restrict__ ali = alibi + (size_t)h * MEMLEN + s * CHUNK;
    const size_t off0 = base + (size_t)(s * CHUNK) * DMODEL;

    #pragma unroll 4
    for (int i = 0; i < CHUNK; i++) {
        const size_t off = off0 + (size_t)i * DMODEL;
        const float4 kv = *(const float4*)&Kd[off];
        const float4 vv = *(const float4*)&Vd[off];
        float d = kv.x * qv.x + kv.y * qv.y + kv.z * qv.z + kv.w * qv.w;
        d += __shfl_xor(d, 1);
        d += __shfl_xor(d, 2);
        d += __shfl_xor(d, 4);
        d += __shfl_xor(d, 8);
        const float pw = __expf(d + ali[i]);
        l += pw;
        acc.x += pw * vv.x;
        acc.y += pw * vv.y;
        acc.z += pw * vv.z;
        acc.w += pw * vv.w;
    }
    *(f32x4*)&pacc[((size_t)(b * SPLIT + s)) * DMODEL + 4 * t] = acc;
    if ((t & 15) == 0) pl[(b * SPLIT + s) * NHEADS + h] = l;
}

// Combine SPLIT partials -> attn (bf16, ready as Wo's A operand). Grid 128.
__global__ __launch_bounds__(256) void attn_combine_k(
    const float* __restrict__ pacc, const float* __restrict__ pl,
    __bf16* __restrict__ attnb)
{
    const int b = blockIdx.x;
    const int t = threadIdx.x;
    const int h = t >> 4;

    float  L   = 0.0f;
    float4 acc = {0.f, 0.f, 0.f, 0.f};
    #pragma unroll
    for (int s = 0; s < SPLIT; s++) {
        L += pl[(b * SPLIT + s) * NHEADS + h];
        const float4 pa = *(const float4*)
            &pacc[((size_t)(b * SPLIT + s)) * DMODEL + 4 * t];
        acc.x += pa.x; acc.y += pa.y; acc.z += pa.z; acc.w += pa.w;
    }
    const float inv = 1.0f / L;
    bf16x4 o;
    o[0] = (__bf16)(acc.x * inv); o[1] = (__bf16)(acc.y * inv);
    o[2] = (__bf16)(acc.z * inv); o[3] = (__bf16)(acc.w * inv);
    *(bf16x4*)&attnb[(size_t)b * DMODEL + 4 * t] = o;
}

// out = LN(x + sum_z parts[z]) * g + be; optional bf16 copy. Grid 128.
template<int NPARTS, bool WRITE_BF16>
__global__ __launch_bounds__(256) void ln_k(
    const float* __restrict__ xres, const float* __restrict__ parts,
    const float* __restrict__ g, const float* __restrict__ be,
    float* __restrict__ of32, __bf16* __restrict__ obf)
{
    const int b = blockIdx.x;
    const int t = threadIdx.x;
    float4 sv = *(const float4*)&xres[(size_t)b * DMODEL + 4 * t];
    #pragma unroll
    for (int z = 0; z < NPARTS; z++) {
        const float4 yv = *(const float4*)
            &parts[(size_t)z * (BATCH * DMODEL) + (size_t)b * DMODEL + 4 * t];
        sv.x += yv.x; sv.y += yv.y; sv.z += yv.z; sv.w += yv.w;
    }
    float sum = sv.x + sv.y + sv.z + sv.w;
    float sq  = sv.x * sv.x + sv.y * sv.y + sv.z * sv.z + sv.w * sv.w;
    #pragma unroll
    for (int mask = 1; mask < 64; mask <<= 1) {
        sum += __shfl_xor(sum, mask);
        sq  += __shfl_xor(sq, mask);
    }
    __shared__ float red[8];
    const int w = t >> 6;
    if ((t & 63) == 0) { red[w * 2] = sum; red[w * 2 + 1] = sq; }
    __syncthreads();
    sum = red[0] + red[2] + red[4] + red[6];
    sq  = red[1] + red[3] + red[5] + red[7];

    const float mu  = sum * (1.0f / DMODEL);
    const float var = sq * (1.0f / DMODEL) - mu * mu;
    const float rs  = rsqrtf(var + 1e-5f);

    const float4 gv  = *(const float4*)&g[4 * t];
    const float4 bev = *(const float4*)&be[4 * t];
    float4 o;
    o.x = (sv.x - mu) * rs * gv.x + bev.x;
    o.y = (sv.y - mu) * rs * gv.y + bev.y;
    o.z = (sv.z - mu) * rs * gv.z + bev.z;
    o.w = (sv.w - mu) * rs * gv.w + bev.w;
    *(float4*)&of32[(size_t)b * DMODEL + 4 * t] = o;
    if constexpr (WRITE_BF16) {
        bf16x4 ob;
        ob[0] = (__bf16)o.x; ob[1] = (__bf16)o.y;
        ob[2] = (__bf16)o.z; ob[3] = (__bf16)o.w;
        *(bf16x4*)&obf[(size_t)b * DMODEL + 4 * t] = ob;
    }
}

// ff1act = relu(sum_z ffbpart[z]) as bf16 (ff2's A operand). Grid 256.
__global__ __launch_bounds__(256) void ff1reduce_k(
    const float* __restrict__ ffbpart, __bf16* __restrict__ ff1act)
{
    const int t = threadIdx.x;
    const size_t base = (size_t)blockIdx.x * 2048 + t * 8;
    float4 s0 = {0.f, 0.f, 0.f, 0.f}, s1 = {0.f, 0.f, 0.f, 0.f};
    #pragma unroll
    for (int z = 0; z < F1SPLIT; z++) {
        const float* pp = ffbpart + (size_t)z * ((size_t)BATCH * DFF) + base;
        const float4 a  = *(const float4*)pp;
        const float4 b4 = *(const float4*)(pp + 4);
        s0.x += a.x;  s0.y += a.y;  s0.z += a.z;  s0.w += a.w;
        s1.x += b4.x; s1.y += b4.y; s1.z += b4.z; s1.w += b4.w;
    }
    bf16x8 o;
    o[0] = (__bf16)fmaxf(s0.x, 0.f); o[1] = (__bf16)fmaxf(s0.y, 0.f);
    o[2] = (__bf16)fmaxf(s0.z, 0.f); o[3] = (__bf16)fmaxf(s0.w, 0.f);
    o[4] = (__bf16)fmaxf(s1.x, 0.f); o[5] = (__bf16)fmaxf(s1.y, 0.f);
    o[6] = (__bf16)fmaxf(s1.z, 0.f); o[7] = (__bf16)fmaxf(s1.w, 0.f);
    *(bf16x8*)&ff1act[base] = o;
}

// ---------------------------------------------------------------------------
extern "C" void kernel_launch(void* const* d_in, const int* in_sizes, int n_in,
                              void* d_out, int out_size, void* d_ws, size_t ws_size,
                              hipStream_t stream)
{
    const float* x   = (const float*)d_in[0];
    const float* mk  = (const float*)d_in[1];
    const float* mv  = (const float*)d_in[2];
    const float* ab  = (const float*)d_in[3];
    const float* Wq  = (const float*)d_in[4];
    const float* bq  = (const float*)d_in[5];
    const float* Wo  = (const float*)d_in[6];
    const float* bo  = (const float*)d_in[7];
    const float* W1  = (const float*)d_in[8];
    const float* b1  = (const float*)d_in[9];
    const float* W2  = (const float*)d_in[10];
    const float* b2  = (const float*)d_in[11];
    const float* g1  = (const float*)d_in[12];
    const float* be1 = (const float*)d_in[13];
    const float* g2  = (const float*)d_in[14];
    const float* be2 = (const float*)d_in[15];
    float* out = (float*)d_out;

    // Workspace layout (floats); every buffer fully written before read.
    float* wsf      = (float*)d_ws;
    float* qpart    = wsf;                 // 8 x 131072 = 1048576
    float* qsum     = wsf + 1048576;       // 131072
    float* tmppart  = wsf + 1179648;       // 8 x 131072 = 1048576
    float* hbuf     = wsf + 2228224;       // 131072
    float* ffbpart  = wsf + 2359296;       // 4 x 524288 = 2097152
    float* tmp2part = wsf + 4456448;       // 16 x 131072 = 2097152
    float* pacc     = wsf + 6553600;       // 8 x 131072 = 1048576
    float* pl       = wsf + 7602176;       // 16384
    __bf16* attnb   = (__bf16*)(wsf + 7618560);   // 131072 bf16
    __bf16* hbf     = (__bf16*)(wsf + 7684096);   // 131072 bf16
    __bf16* ff1act  = (__bf16*)(wsf + 7749632);   // 524288 bf16

    // 1. q partials = x @ Wq + bq  (fp32 A; 256 blocks)
    gemm_k<0, DMODEL / QSPLIT><<<dim3(16, 2, QSPLIT), 256, 0, stream>>>(
        x, nullptr, Wq, bq, qpart, DMODEL, DMODEL);
    // 1.5 qsum = 0.125 * sum(qpart)
    qsum_k<<<BATCH, 256, 0, stream>>>(qpart, qsum);
    // 2. flash-decode attention partials (the 1 GB K/V stream)
    attn_partial_k<<<dim3(SPLIT, BATCH), 256, 0, stream>>>(
        qsum, mk, mv, ab, pacc, pl);
    // 3. combine -> attn (bf16)
    attn_combine_k<<<BATCH, 256, 0, stream>>>(pacc, pl, attnb);
    // 4. attn-proj partials = attn @ Wo + bo  (bf16 A; 256 blocks)
    gemm_k<1, DMODEL / QSPLIT><<<dim3(16, 2, QSPLIT), 256, 0, stream>>>(
        nullptr, attnb, Wo, bo, tmppart, DMODEL, DMODEL);
    // 5. h = LN(x + attn_proj); fp32 + bf16 copies
    ln_k<QSPLIT, true><<<BATCH, 256, 0, stream>>>(
        x, tmppart, g1, be1, hbuf, hbf);
    // 6. ff1 partials = h @ W1 + b1  (bf16 A; 512 blocks)
    gemm_k<1, DMODEL / F1SPLIT><<<dim3(64, 2, F1SPLIT), 256, 0, stream>>>(
        nullptr, hbf, W1, b1, ffbpart, DFF, DMODEL);
    // 6.5 ff1act = relu(sum(ffbpart)) as bf16
    ff1reduce_k<<<(BATCH * DFF) / 2048, 256, 0, stream>>>(ffbpart, ff1act);
    // 7. ff2 partials = ff1act @ W2 + b2  (bf16 A; 512 blocks)
    gemm_k<1, DFF / F2SPLIT><<<dim3(16, 2, F2SPLIT), 256, 0, stream>>>(
        nullptr, ff1act, W2, b2, tmp2part, DMODEL, DFF);
    // 8. out = LN(h + ff2)
    ln_k<F2SPLIT, false><<<BATCH, 256, 0, stream>>>(
        hbuf, tmp2part, g2, be2, out, nullptr);
}